// Round 3
// baseline (103.091 us; speedup 1.0000x reference)
//
#include <hip/hip_runtime.h>

// B=32, C=8, L=2048, K=512, S=64, W=1985
// out[b,0,q] = max(0, max_w sum_c dot(xw_n[b,c,w,:], sn_n[c,q,:]) / 8)

#define B_ 32
#define C_ 8
#define L_ 2048
#define K_ 512
#define S_ 64
#define W_ (L_ - S_ + 1)              // 1985
#define TW 128                        // windows per block
#define NWT ((W_ + TW - 1) / TW)      // 16 window tiles
#define XP 192                        // xl row stride (floats), need 191

typedef _Float16 f16x8 __attribute__((ext_vector_type(8)));
typedef float f32x4 __attribute__((ext_vector_type(4)));

// ---- kernel 1: normalize shapelets -> fp16 B-fragment layout; also zero out.
// Bp unit index: ((c*2+ks)*32 + ntg)*64 + lane,  value[j] = sn[c][ntg*16+(lane&15)]
//   [ks*32 + (lane>>4)*8 + j] * invnorm
__global__ __launch_bounds__(256)
void pack_sn_k(const float* __restrict__ sh, _Float16* __restrict__ Bp,
               float* __restrict__ out) {
    const int tid = threadIdx.x;
    // zero the output (replaces a hipMemsetAsync dispatch)
    int gid = blockIdx.x * 256 + tid;
    if (gid < B_ * K_) out[gid] = 0.f;

    const int blk  = blockIdx.x * 4 + (tid >> 6);  // 0..511 = c(8) x ks(2) x nt(32)
    const int c    = blk >> 6;
    const int ks   = (blk >> 5) & 1;
    const int nt   = blk & 31;
    const int lane = tid & 63;
    const int ncol = lane & 15, quad = lane >> 4;
    const int q    = nt * 16 + ncol;

    const float4* sp = (const float4*)(sh + (size_t)(c * K_ + q) * S_);
    float ss = 0.f;
    #pragma unroll
    for (int i = 0; i < 4; ++i) {
        float4 v = sp[quad * 4 + i];
        ss += v.x * v.x + v.y * v.y + v.z * v.z + v.w * v.w;
    }
    ss += __shfl_xor(ss, 16);
    ss += __shfl_xor(ss, 32);
    float inv = 1.f / fmaxf(sqrtf(ss), 1e-8f);

    float4 u0 = sp[ks * 8 + quad * 2];
    float4 u1 = sp[ks * 8 + quad * 2 + 1];
    f16x8 o;
    o[0] = (_Float16)(u0.x * inv); o[1] = (_Float16)(u0.y * inv);
    o[2] = (_Float16)(u0.z * inv); o[3] = (_Float16)(u0.w * inv);
    o[4] = (_Float16)(u1.x * inv); o[5] = (_Float16)(u1.y * inv);
    o[6] = (_Float16)(u1.z * inv); o[7] = (_Float16)(u1.w * inv);
    ((f16x8*)Bp)[((c * 2 + ks) * 32 + nt) * 64 + lane] = o;
}

// ---- kernel 2: MFMA GEMM + relu + max ----
// grid (NWT, B_), 512 threads = 8 waves = 2 m-groups x 4 n-waves.
// K processed in 4 phases of 2 channels; Ah (32 KB) holds pre-scaled f16
// A-fragments in exact MFMA layout, rebuilt each phase.
__global__ __launch_bounds__(512, 2)
void mcs_mfma_k(const float* __restrict__ x, const _Float16* __restrict__ Bp,
                float* __restrict__ out) {
    __shared__ float xl[C_ * XP];        // 6 KB   x slice fp32
    __shared__ f16x8 AhV[32 * 64];       // 32 KB  A-fragments for 2 channels
    __shared__ float psum[512];          // 2 KB   norm partial sums

    const int wt  = blockIdx.x;
    const int b   = blockIdx.y;
    const int w0  = wt * TW;
    const int tid = threadIdx.x;

    // stage x[b, c, w0 .. w0+190], zero-fill OOB (191 floats/channel)
    for (int i = tid; i < C_ * XP; i += 512) {
        int c = i / XP, p = i - c * XP;
        int pos = w0 + p;
        float v = 0.f;
        if (p < 191 && pos < L_) v = x[(size_t)(b * C_ + c) * L_ + pos];
        xl[i] = v;
    }

    const int lane = tid & 63;
    const int wid  = tid >> 6;
    const int g    = wid >> 2;          // m-group: windows [g*64, g*64+64)
    const int nw   = wid & 3;           // n-wave: cols [nw*128, ..)
    const int row  = lane & 15;
    const int quad = lane >> 4;

    // build-role indices: thread handles half a window-row
    const int r_  = tid & 255;          // row id: cc(2) x w(128)
    const int h_  = tid >> 8;           // s-half == ks
    const int cc_ = r_ >> 7;
    const int w_  = r_ & 127;

    f32x4 acc[4][8];
    #pragma unroll
    for (int mt = 0; mt < 4; ++mt)
        #pragma unroll
        for (int nt = 0; nt < 8; ++nt)
            acc[mt][nt] = (f32x4){0.f, 0.f, 0.f, 0.f};

    #pragma unroll 1
    for (int ph = 0; ph < 4; ++ph) {
        const int c0 = ph * 2;
        __syncthreads();                 // xl staged / prev consume done

        // ---- build: row (c0+cc_, w_), s in [h_*32, h_*32+32) ----
        float xv[32];
        {
            const float* xp = xl + (c0 + cc_) * XP + w_ + h_ * 32;
            float s0 = 0.f, s1 = 0.f, s2 = 0.f, s3 = 0.f;
            #pragma unroll
            for (int i = 0; i < 32; i += 4) {
                xv[i] = xp[i]; xv[i+1] = xp[i+1];
                xv[i+2] = xp[i+2]; xv[i+3] = xp[i+3];
                s0 += xv[i]*xv[i];     s1 += xv[i+1]*xv[i+1];
                s2 += xv[i+2]*xv[i+2]; s3 += xv[i+3]*xv[i+3];
            }
            psum[tid] = (s0 + s1) + (s2 + s3);
        }
        __syncthreads();
        {
            float sst = psum[r_] + psum[r_ + 256];
            float inv = 0.125f / fmaxf(sqrtf(sst), 1e-8f);
            const int fb = (cc_ * 2 + h_) * 8 + (w_ >> 4);
            #pragma unroll
            for (int qd = 0; qd < 4; ++qd) {
                f16x8 o;
                #pragma unroll
                for (int j = 0; j < 8; ++j)
                    o[j] = (_Float16)(xv[qd * 8 + j] * inv);
                AhV[fb * 64 + qd * 16 + (w_ & 15)] = o;
            }
        }
        __syncthreads();

        // ---- consume: 2 channels x 2 k-halves ----
        #pragma unroll
        for (int cc = 0; cc < 2; ++cc) {
            #pragma unroll
            for (int ks = 0; ks < 2; ++ks) {
                f16x8 af[4];
                const int fb = (cc * 2 + ks) * 8 + g * 4;
                #pragma unroll
                for (int mt = 0; mt < 4; ++mt)
                    af[mt] = AhV[(fb + mt) * 64 + lane];

                const f16x8* bpp = (const f16x8*)Bp +
                    (((c0 + cc) * 2 + ks) * 32 + nw * 8) * 64 + lane;
                f16x8 bf[8];
                #pragma unroll
                for (int nt = 0; nt < 8; ++nt) bf[nt] = bpp[nt * 64];

                #pragma unroll
                for (int nt = 0; nt < 8; ++nt)
                    #pragma unroll
                    for (int mt = 0; mt < 4; ++mt)
                        acc[mt][nt] = __builtin_amdgcn_mfma_f32_16x16x32_f16(
                            af[mt], bf[nt], acc[mt][nt], 0, 0, 0);
            }
        }
    }

    // epilogue: relu + max over windows; C/D: col=lane&15, row=quad*4+rr
    #pragma unroll
    for (int nt = 0; nt < 8; ++nt) {
        float m = 0.f;
        #pragma unroll
        for (int mt = 0; mt < 4; ++mt) {
            #pragma unroll
            for (int rr = 0; rr < 4; ++rr) {
                int w = w0 + g * 64 + mt * 16 + quad * 4 + rr;
                if (w < W_) m = fmaxf(m, acc[mt][nt][rr]);
            }
        }
        m = fmaxf(m, __shfl_xor(m, 16));
        m = fmaxf(m, __shfl_xor(m, 32));
        if (lane < 16)
            atomicMax((unsigned int*)(out + b * K_ + (nw * 8 + nt) * 16 + lane),
                      __float_as_uint(m));
    }
}

extern "C" void kernel_launch(void* const* d_in, const int* in_sizes, int n_in,
                              void* d_out, int out_size, void* d_ws, size_t ws_size,
                              hipStream_t stream) {
    const float* x  = (const float*)d_in[0];   // (32, 8, 2048) fp32
    const float* sh = (const float*)d_in[1];   // (8, 512, 64) fp32
    float* out = (float*)d_out;                // (32, 1, 512) fp32
    _Float16* Bp = (_Float16*)d_ws;            // 512 KB packed shapelets

    pack_sn_k<<<dim3(128), dim3(256), 0, stream>>>(sh, Bp, out);
    mcs_mfma_k<<<dim3(NWT, B_), dim3(512), 0, stream>>>(x, Bp, out);
}